// Round 1
// 3262.579 us; speedup vs baseline: 1.3514x; 1.3514x over previous
//
#include <hip/hip_runtime.h>
#include <hip/hip_bf16.h>
#include <math.h>

// ---------------------------------------------------------------------------
// NaiveAttentionModel forward on MI355X (gfx950).
// fp32 residual, bf16 MFMA operands. 12-layer pre-LN transformer:
// B=2, L=1024, E=1024, H=16, Dh=64, MLP 4E.
// This round: fused causal flash attention (replaces scores GEMM + softmax +
// PV GEMM and all S/P materialization), proj/w2 GEMMs -> 256-WG config.
// ---------------------------------------------------------------------------

typedef __hip_bfloat16 bf16;
typedef __attribute__((ext_vector_type(8))) short short8;   // 8 x bf16 (4 VGPRs)
typedef __attribute__((ext_vector_type(4))) float f32x4;    // MFMA acc

#define NLAYER 12
#define NH     16
#define EDIM   1024
#define DIN    64
#define BATCH  2
#define KCTX   512
#define LSEQ   1024      // 2*KCTX
#define MTOK   2048      // BATCH*LSEQ
#define DH     64
#define E3     3072
#define E4     4096

__device__ __forceinline__ bf16 f2bf(float v) { return __float2bfloat16(v); }

#define USE_GLOBAL_LOAD_LDS 1

// Each lane's 16B at g goes to LDS (wave-uniform base l) + lane*16.
__device__ __forceinline__ void gld_lds16(const bf16* g, bf16* l, int lane) {
#if USE_GLOBAL_LOAD_LDS
  (void)lane;
  __builtin_amdgcn_global_load_lds(
      (const __attribute__((address_space(1))) void*)g,
      (__attribute__((address_space(3))) void*)l, 16, 0, 0);
#else
  ((short8*)l)[lane] = *(const short8*)g;
#endif
}

enum { EPI_BIAS_BF16 = 0, EPI_BIAS_GELU_BF16, EPI_BIAS_RES_F32, EPI_SCORES, EPI_BF16 };

// C[M][N] = A[M][K] * Bt[N][K]^T (+bias/+residual/GELU per EPI).
// A, Bt are bf16 (internal buffers). bias/res fp32.
template <int BM, int BN, int WGM, int WGN, int EPI>
__global__ __launch_bounds__(256) void gemm_bt(
    const bf16* __restrict__ A, int lda, long sAz,
    const bf16* __restrict__ Bt, int ldb, long sBz,
    void* Cout, int ldc, long sCz,
    const float* __restrict__ bias,
    const float* res, int Kdim)
{
  constexpr int BK = 32;
  constexpr int WM = BM / WGM, WN = BN / WGN;
  constexpr int TM = WM / 16, TN = WN / 16;
  constexpr int CA = BM / 64, CB = BN / 64;   // 1KB LDS chunks per wave
  static_assert(WGM * WGN == 4, "4 waves");
  static_assert(BM % 64 == 0 && BN % 64 == 0, "");

  __shared__ bf16 As[BM * BK];
  __shared__ bf16 Bs[BN * BK];

  const int z = blockIdx.z;
  A  += (long)z * sAz;
  Bt += (long)z * sBz;
  const long m0 = (long)blockIdx.y * BM;
  const long n0 = (long)blockIdx.x * BN;
  const int tid  = threadIdx.x;
  const int wv   = __builtin_amdgcn_readfirstlane(tid >> 6);
  const int lane = tid & 63;
  const int l15  = lane & 15, q4 = lane >> 4;
  const int wr = wv / WGN, wc = wv % WGN;
  const int arow = lane >> 2;          // 0..15 (row within 16-row chunk)
  const int acol = (lane & 3) * 8;     // 0,8,16,24 (k offset)

  f32x4 acc[TM][TN];
#pragma unroll
  for (int i = 0; i < TM; ++i)
#pragma unroll
    for (int j = 0; j < TN; ++j)
      acc[i][j] = (f32x4){0.f, 0.f, 0.f, 0.f};

  for (int k0 = 0; k0 < Kdim; k0 += BK) {
#pragma unroll
    for (int c = 0; c < CA; ++c) {
      const int chunk = wv * CA + c;
      const int row = chunk * 16 + arow;
      gld_lds16(A + (m0 + row) * lda + k0 + acol, As + chunk * 512, lane);
    }
#pragma unroll
    for (int c = 0; c < CB; ++c) {
      const int chunk = wv * CB + c;
      const int row = chunk * 16 + arow;
      gld_lds16(Bt + (n0 + row) * ldb + k0 + acol, Bs + chunk * 512, lane);
    }
    __syncthreads();   // drains vmcnt(0) before s_barrier (DMA complete)

    short8 af[TM], bfv[TN];
#pragma unroll
    for (int i = 0; i < TM; ++i)
      af[i] = *(const short8*)(As + (wr * WM + i * 16 + l15) * BK + q4 * 8);
#pragma unroll
    for (int j = 0; j < TN; ++j)
      bfv[j] = *(const short8*)(Bs + (wc * WN + j * 16 + l15) * BK + q4 * 8);
#pragma unroll
    for (int i = 0; i < TM; ++i)
#pragma unroll
      for (int j = 0; j < TN; ++j)
        acc[i][j] = __builtin_amdgcn_mfma_f32_16x16x32_bf16(af[i], bfv[j], acc[i][j], 0, 0, 0);
    __syncthreads();
  }

  const long zC = (long)z * sCz;
#pragma unroll
  for (int i = 0; i < TM; ++i) {
#pragma unroll
    for (int j = 0; j < TN; ++j) {
      const long gn = n0 + wc * WN + j * 16 + l15;
      float bv = 0.f;
      if (EPI == EPI_BIAS_BF16 || EPI == EPI_BIAS_GELU_BF16 || EPI == EPI_BIAS_RES_F32)
        bv = bias[gn];
#pragma unroll
      for (int r = 0; r < 4; ++r) {
        const long gm = m0 + wr * WM + i * 16 + q4 * 4 + r;
        const long idx = zC + gm * ldc + gn;
        float v = acc[i][j][r];
        if (EPI == EPI_BIAS_BF16) {
          ((bf16*)Cout)[idx] = f2bf(v + bv);
        } else if (EPI == EPI_BIAS_GELU_BF16) {
          float t = v + bv;
          t = 0.5f * t * (1.0f + erff(t * 0.70710678118654752f));  // exact GELU
          ((bf16*)Cout)[idx] = f2bf(t);
        } else if (EPI == EPI_BIAS_RES_F32) {
          ((float*)Cout)[idx] = v + bv + res[idx];   // res aliases Cout (same elem)
        } else if (EPI == EPI_SCORES) {
          v *= 0.125f;
          if (gn > gm) v = -1e9f;
          ((float*)Cout)[idx] = v;
        } else { // EPI_BF16
          ((bf16*)Cout)[idx] = f2bf(v);
        }
      }
    }
  }
}

// ---------------------------------------------------------------------------
// Fused causal flash attention.
// Grid: x = q-tile (L/128 = 8), y = bh (B*NH = 32). 256 threads / 4 waves.
// Wave wv owns q-rows [wv*32, wv*32+32) of the 128-row q-tile.
// Per k-tile (128 keys): stage K[2][128][32] + V[4][64][32] in LDS (GEMM chunk
// layout), S = Q K^T via mfma (rows=q, cols=k), online softmax (row stats per
// (i,r) pair, reduced over the 16-lane col group), P -> per-wave XOR-swizzled
// LDS tile, O += P V. Causal: loop k0 <= q0; mask only the diagonal tile.
// ---------------------------------------------------------------------------
__global__ __launch_bounds__(256) void flash_kernel(
    const bf16* __restrict__ qkv, const bf16* __restrict__ vT,
    bf16* __restrict__ o)
{
  const int qt = blockIdx.x;
  const int bh = blockIdx.y;
  const int b  = bh >> 4, h = bh & 15;
  const int q0 = qt * 128;
  const int tid  = threadIdx.x;
  const int wv   = __builtin_amdgcn_readfirstlane(tid >> 6);
  const int lane = tid & 63;
  const int l15  = lane & 15, q4 = lane >> 4;

  __shared__ __align__(16) bf16 Ks[2 * 128 * 32];   // [kk][krow][32]
  __shared__ __align__(16) bf16 Vs[4 * 64 * 32];    // [kstep][d][32]
  __shared__ __align__(16) bf16 Pl[4][32 * 128];    // per-wave P, XOR-swizzled

  // Q fragments (A operand) resident in registers: row = l15, k = q4*8.
  short8 qf[2][2];
  {
    const bf16* qb = qkv + (size_t)(b * LSEQ + q0 + wv * 32 + l15) * E3 + h * DH + q4 * 8;
#pragma unroll
    for (int i = 0; i < 2; ++i)
#pragma unroll
      for (int kk = 0; kk < 2; ++kk)
        qf[i][kk] = *(const short8*)(qb + (size_t)i * 16 * E3 + kk * 32);
  }

  f32x4 oacc[2][4];
#pragma unroll
  for (int i = 0; i < 2; ++i)
#pragma unroll
    for (int jd = 0; jd < 4; ++jd)
      oacc[i][jd] = (f32x4){0.f, 0.f, 0.f, 0.f};
  float mrow[2][4], lrow[2][4];
#pragma unroll
  for (int i = 0; i < 2; ++i)
#pragma unroll
    for (int r = 0; r < 4; ++r) { mrow[i][r] = -1e30f; lrow[i][r] = 0.f; }

  const bf16* kg = qkv + (size_t)b * LSEQ * E3 + EDIM + h * DH;
  const bf16* vg = vT + (size_t)bh * DH * LSEQ;
  const int qrow0 = q0 + wv * 32;
  bf16* const pbase = &Pl[wv][0];

  for (int k0 = 0; k0 <= q0; k0 += 128) {
    // ---- stage K (16KB) and V (16KB) tiles via global_load_lds ----
#pragma unroll
    for (int c = 0; c < 4; ++c) {
      const int ci = c * 4 + wv;                 // 0..15
      const int kk = ci >> 3, rowb = (ci & 7) * 16;
      gld_lds16(kg + (size_t)(k0 + rowb + (lane >> 2)) * E3 + kk * 32 + (lane & 3) * 8,
                Ks + ci * 512, lane);
    }
#pragma unroll
    for (int c = 0; c < 4; ++c) {
      const int ci = c * 4 + wv;                 // 0..15
      const int ks = ci >> 2, rowb = (ci & 3) * 16;
      gld_lds16(vg + (size_t)(rowb + (lane >> 2)) * LSEQ + k0 + ks * 32 + (lane & 3) * 8,
                Vs + ci * 512, lane);
    }
    __syncthreads();

    // ---- S = Q K^T: s[i][j] reg r -> q = qrow0+i*16+q4*4+r, k = k0+j*16+l15
    f32x4 s[2][8];
#pragma unroll
    for (int i = 0; i < 2; ++i)
#pragma unroll
      for (int j = 0; j < 8; ++j)
        s[i][j] = (f32x4){0.f, 0.f, 0.f, 0.f};
#pragma unroll
    for (int j = 0; j < 8; ++j) {
      const short8 kf0 = *(const short8*)(Ks + (j * 16 + l15) * 32 + q4 * 8);
      const short8 kf1 = *(const short8*)(Ks + 4096 + (j * 16 + l15) * 32 + q4 * 8);
#pragma unroll
      for (int i = 0; i < 2; ++i) {
        s[i][j] = __builtin_amdgcn_mfma_f32_16x16x32_bf16(qf[i][0], kf0, s[i][j], 0, 0, 0);
        s[i][j] = __builtin_amdgcn_mfma_f32_16x16x32_bf16(qf[i][1], kf1, s[i][j], 0, 0, 0);
      }
    }

    const bool diag = (k0 == q0);
    // ---- online softmax (per (i,r) = one q-row per 16-lane group) ----
#pragma unroll
    for (int i = 0; i < 2; ++i) {
#pragma unroll
      for (int r = 0; r < 4; ++r) {
        const int lr   = i * 16 + q4 * 4 + r;   // local q-row 0..31
        const int qrow = qrow0 + lr;
        float mx = -1e30f;
#pragma unroll
        for (int j = 0; j < 8; ++j) {
          float v = s[i][j][r] * 0.125f;
          if (diag && (k0 + j * 16 + l15 > qrow)) v = -1e30f;
          s[i][j][r] = v;
          mx = fmaxf(mx, v);
        }
        mx = fmaxf(mx, __shfl_xor(mx, 1, 64));
        mx = fmaxf(mx, __shfl_xor(mx, 2, 64));
        mx = fmaxf(mx, __shfl_xor(mx, 4, 64));
        mx = fmaxf(mx, __shfl_xor(mx, 8, 64));
        const float mnew = fmaxf(mrow[i][r], mx);
        const float corr = __expf(mrow[i][r] - mnew);
        mrow[i][r] = mnew;
        float rs = 0.f;
#pragma unroll
        for (int j = 0; j < 8; ++j) {
          const float p = __expf(s[i][j][r] - mnew);
          rs += p;
          // swizzled write: byte = (row*256 + col*2) ^ ((row&7)<<4)
          *(bf16*)((char*)pbase +
                   (((lr * 256) + (j * 16 + l15) * 2) ^ ((lr & 7) << 4))) = f2bf(p);
        }
        rs += __shfl_xor(rs, 1, 64);
        rs += __shfl_xor(rs, 2, 64);
        rs += __shfl_xor(rs, 4, 64);
        rs += __shfl_xor(rs, 8, 64);
        lrow[i][r] = lrow[i][r] * corr + rs;
#pragma unroll
        for (int jd = 0; jd < 4; ++jd) oacc[i][jd][r] *= corr;
      }
    }

    // ---- O += P V ----
#pragma unroll
    for (int ks = 0; ks < 4; ++ks) {
      short8 paf[2], vf[4];
#pragma unroll
      for (int i = 0; i < 2; ++i) {
        const int rr = i * 16 + l15;
        paf[i] = *(const short8*)((const char*)pbase +
                  ((rr * 256 + ks * 64 + q4 * 16) ^ ((rr & 7) << 4)));
      }
#pragma unroll
      for (int jd = 0; jd < 4; ++jd)
        vf[jd] = *(const short8*)(Vs + ks * 2048 + (jd * 16 + l15) * 32 + q4 * 8);
#pragma unroll
      for (int i = 0; i < 2; ++i)
#pragma unroll
        for (int jd = 0; jd < 4; ++jd)
          oacc[i][jd] = __builtin_amdgcn_mfma_f32_16x16x32_bf16(paf[i], vf[jd], oacc[i][jd], 0, 0, 0);
    }
    __syncthreads();   // before next tile overwrites Ks/Vs
  }

  // ---- normalize & store ----
  bf16* ob = o + (size_t)(b * LSEQ + qrow0) * EDIM + h * DH;
#pragma unroll
  for (int i = 0; i < 2; ++i) {
#pragma unroll
    for (int r = 0; r < 4; ++r) {
      const float inv = 1.f / lrow[i][r];
      const int row = i * 16 + q4 * 4 + r;
#pragma unroll
      for (int jd = 0; jd < 4; ++jd)
        ob[(size_t)row * EDIM + jd * 16 + l15] = f2bf(oacc[i][jd][r] * inv);
    }
  }
}

// x[m][e] (fp32) from interleaved tokens: even = xs @ w_in, odd = y * w_in[0,:].
__global__ __launch_bounds__(256) void embed_kernel(
    const float* __restrict__ xs, const float* __restrict__ ys,
    const float* __restrict__ w_in, const float* __restrict__ b_in,
    float* __restrict__ x)
{
  const int m = blockIdx.x;
  const int b = m >> 10, tok = m & 1023, l = tok >> 1;
  const int t = threadIdx.x, c = t * 4;
  float a0, a1, a2, a3;
  if (tok & 1) {
    const float y = ys[b * KCTX + l];
    a0 = y * w_in[c + 0]; a1 = y * w_in[c + 1];
    a2 = y * w_in[c + 2]; a3 = y * w_in[c + 3];
  } else {
    __shared__ float xv[DIN];
    if (t < DIN) xv[t] = xs[((size_t)b * KCTX + l) * DIN + t];
    __syncthreads();
    a0 = a1 = a2 = a3 = 0.f;
#pragma unroll 8
    for (int d = 0; d < DIN; ++d) {
      const float xd = xv[d];
      const float* wr = w_in + d * EDIM + c;
      a0 += xd * wr[0]; a1 += xd * wr[1];
      a2 += xd * wr[2]; a3 += xd * wr[3];
    }
  }
  a0 += b_in[c + 0]; a1 += b_in[c + 1];
  a2 += b_in[c + 2]; a3 += b_in[c + 3];
  *(float4*)(x + (size_t)m * EDIM + c) = make_float4(a0, a1, a2, a3);
}

// LayerNorm (biased var) fp32 -> bf16, one block per row.
__global__ __launch_bounds__(256) void ln_kernel(
    const float* __restrict__ x, const float* __restrict__ gam,
    const float* __restrict__ bet, bf16* __restrict__ h)
{
  const int row = blockIdx.x, t = threadIdx.x;
  const float4 v = ((const float4*)(x + (size_t)row * EDIM))[t];
  float s = v.x + v.y + v.z + v.w;
  float q = v.x * v.x + v.y * v.y + v.z * v.z + v.w * v.w;
#pragma unroll
  for (int m = 32; m > 0; m >>= 1) { s += __shfl_xor(s, m, 64); q += __shfl_xor(q, m, 64); }
  __shared__ float sred[4], qred[4];
  if ((t & 63) == 0) { sred[t >> 6] = s; qred[t >> 6] = q; }
  __syncthreads();
  s = sred[0] + sred[1] + sred[2] + sred[3];
  q = qred[0] + qred[1] + qred[2] + qred[3];
  const float mean = s * (1.f / EDIM);
  const float var  = q * (1.f / EDIM) - mean * mean;
  const float rstd = rsqrtf(var + 1e-5f);
  const int c = t * 4;
  alignas(8) bf16 o[4];
  o[0] = f2bf((v.x - mean) * rstd * gam[c + 0] + bet[c + 0]);
  o[1] = f2bf((v.y - mean) * rstd * gam[c + 1] + bet[c + 1]);
  o[2] = f2bf((v.z - mean) * rstd * gam[c + 2] + bet[c + 2]);
  o[3] = f2bf((v.w - mean) * rstd * gam[c + 3] + bet[c + 3]);
  *(uint2*)(h + (size_t)row * EDIM + c) = *(uint2*)o;
}

// V slice of qkv (bf16) -> vT[b*16+h][d][l]  (64x64 tiles via LDS).
__global__ __launch_bounds__(256) void vtrans_kernel(
    const bf16* __restrict__ qkv, bf16* __restrict__ vT)
{
  const int bh = blockIdx.y;            // b*16+h
  const int b = bh >> 4, hh = bh & 15;
  const int l0 = blockIdx.x * 64;
  __shared__ bf16 tile[64][68];
  const int t = threadIdx.x;
  const int sub = t >> 6, ll = t & 63;
#pragma unroll
  for (int r = 0; r < 16; ++r) {
    const int lr = sub * 16 + r;
    tile[lr][ll] = qkv[(size_t)(b * LSEQ + l0 + lr) * E3 + 2048 + hh * 64 + ll];
  }
  __syncthreads();
#pragma unroll
  for (int r = 0; r < 16; ++r) {
    const int d = sub * 16 + r;
    vT[((size_t)bh * DH + d) * LSEQ + l0 + ll] = tile[ll][d];
  }
}

// Transpose+convert this layer's 4 weight mats W[K][N] fp32 -> Wt[N][K] bf16.
__global__ __launch_bounds__(256) void wtrans4_kernel(
    const float* __restrict__ qw, const float* __restrict__ pw,
    const float* __restrict__ w1, const float* __restrict__ w2,
    bf16* qT, bf16* pT, bf16* w1T, bf16* w2T)
{
  int id = blockIdx.x;
  const float* src; bf16* dst; int Kd, Nd, tk, tn;
  if (id < 768)       {             src = qw; dst = qT;  Kd = 1024; Nd = 3072; tk = id / 48; tn = id % 48; }
  else if (id < 1024) { id -= 768;  src = pw; dst = pT;  Kd = 1024; Nd = 1024; tk = id / 16; tn = id % 16; }
  else if (id < 2048) { id -= 1024; src = w1; dst = w1T; Kd = 1024; Nd = 4096; tk = id / 64; tn = id % 64; }
  else                { id -= 2048; src = w2; dst = w2T; Kd = 4096; Nd = 1024; tk = id / 16; tn = id % 16; }
  const int k0 = tk * 64, n0 = tn * 64;
  __shared__ bf16 tile[64][68];
  const int t = threadIdx.x;
  const int tr = t >> 4, tv = t & 15;
#pragma unroll
  for (int r = 0; r < 4; ++r) {
    const int kl = r * 16 + tr;
    const float4 v = *(const float4*)(src + (size_t)(k0 + kl) * Nd + n0 + tv * 4);
    tile[kl][tv * 4 + 0] = f2bf(v.x);
    tile[kl][tv * 4 + 1] = f2bf(v.y);
    tile[kl][tv * 4 + 2] = f2bf(v.z);
    tile[kl][tv * 4 + 3] = f2bf(v.w);
  }
  __syncthreads();
#pragma unroll
  for (int r = 0; r < 4; ++r) {
    const int nl = r * 16 + tr;
    alignas(8) bf16 o4[4];
    o4[0] = tile[tv * 4 + 0][nl]; o4[1] = tile[tv * 4 + 1][nl];
    o4[2] = tile[tv * 4 + 2][nl]; o4[3] = tile[tv * 4 + 3][nl];
    *(ushort4*)(dst + (size_t)(n0 + nl) * Kd + k0 + tv * 4) = *(ushort4*)o4;
  }
}

// preds[b][k] = x[b*L + 2k] . w_out + b_out  (fp32 exact; one block per output).
__global__ __launch_bounds__(256) void head_kernel(
    const float* __restrict__ x, const float* __restrict__ w,
    const float* __restrict__ b0, float* __restrict__ out)
{
  const int o = blockIdx.x;              // 0..1023
  const int b = o >> 9, k = o & 511;
  const float* xr = x + (size_t)(b * LSEQ + 2 * k) * EDIM;
  const int t = threadIdx.x, c = t * 4;
  const float4 v = ((const float4*)xr)[t];
  const float4 wv = *(const float4*)(w + c);
  float s = v.x * wv.x + v.y * wv.y + v.z * wv.z + v.w * wv.w;
#pragma unroll
  for (int m = 32; m > 0; m >>= 1) s += __shfl_xor(s, m, 64);
  __shared__ float red[4];
  if ((t & 63) == 0) red[t >> 6] = s;
  __syncthreads();
  if (t == 0) out[o] = red[0] + red[1] + red[2] + red[3] + b0[0];
}

extern "C" void kernel_launch(void* const* d_in, const int* in_sizes, int n_in,
                              void* d_out, int out_size, void* d_ws, size_t ws_size,
                              hipStream_t stream)
{
  const float* xs     = (const float*)d_in[0];
  const float* ys     = (const float*)d_in[1];
  const float* w_in   = (const float*)d_in[2];
  const float* b_in   = (const float*)d_in[3];
  const float* qkv_w  = (const float*)d_in[4];
  const float* qkv_b  = (const float*)d_in[5];
  const float* proj_w = (const float*)d_in[6];
  const float* proj_b = (const float*)d_in[7];
  const float* ln1_s  = (const float*)d_in[8];
  const float* ln1_b  = (const float*)d_in[9];
  const float* ln2_s  = (const float*)d_in[10];
  const float* ln2_b  = (const float*)d_in[11];
  const float* mlp_w1 = (const float*)d_in[12];
  const float* mlp_b1 = (const float*)d_in[13];
  const float* mlp_w2 = (const float*)d_in[14];
  const float* mlp_b2 = (const float*)d_in[15];
  const float* w_out  = (const float*)d_in[16];
  const float* b_out  = (const float*)d_in[17];

  // workspace carve (~60 MB peak; S/P buffers no longer needed)
  char* wsp = (char*)d_ws;
  auto carve = [&](size_t bytes) -> char* {
    char* r = wsp; wsp += (bytes + 255) & ~(size_t)255; return r;
  };
  bf16*  wT_qkv  = (bf16*)carve((size_t)E3 * EDIM * 2);
  bf16*  wT_proj = (bf16*)carve((size_t)EDIM * EDIM * 2);
  bf16*  wT_w1   = (bf16*)carve((size_t)E4 * EDIM * 2);
  bf16*  wT_w2   = (bf16*)carve((size_t)EDIM * E4 * 2);
  float* x       = (float*)carve((size_t)MTOK * EDIM * 4);
  bf16*  h       = (bf16*)carve((size_t)MTOK * EDIM * 2);
  bf16*  qkv     = (bf16*)carve((size_t)MTOK * E3 * 2);
  bf16*  vT      = (bf16*)carve((size_t)BATCH * NH * DH * LSEQ * 2);
  bf16*  o       = (bf16*)carve((size_t)MTOK * EDIM * 2);
  bf16*  mh      = (bf16*)carve((size_t)MTOK * E4 * 2);
  (void)ws_size; (void)in_sizes; (void)n_in; (void)out_size;

  embed_kernel<<<MTOK, 256, 0, stream>>>(xs, ys, w_in, b_in, x);

  for (int l = 0; l < NLAYER; ++l) {
    const float* qw  = qkv_w  + (size_t)l * EDIM * E3;
    const float* qb  = qkv_b  + (size_t)l * E3;
    const float* pw  = proj_w + (size_t)l * EDIM * EDIM;
    const float* pb  = proj_b + (size_t)l * EDIM;
    const float* g1  = ln1_s  + (size_t)l * EDIM;
    const float* be1 = ln1_b  + (size_t)l * EDIM;
    const float* g2  = ln2_s  + (size_t)l * EDIM;
    const float* be2 = ln2_b  + (size_t)l * EDIM;
    const float* m1w = mlp_w1 + (size_t)l * EDIM * E4;
    const float* m1b = mlp_b1 + (size_t)l * E4;
    const float* m2w = mlp_w2 + (size_t)l * E4 * EDIM;
    const float* m2b = mlp_b2 + (size_t)l * EDIM;

    wtrans4_kernel<<<3072, 256, 0, stream>>>(qw, pw, m1w, m2w,
                                             wT_qkv, wT_proj, wT_w1, wT_w2);
    ln_kernel<<<MTOK, 256, 0, stream>>>(x, g1, be1, h);
    gemm_bt<128,128,2,2,EPI_BIAS_BF16><<<dim3(E3/128, MTOK/128, 1), 256, 0, stream>>>(
        h, EDIM, 0, wT_qkv, EDIM, 0, qkv, E3, 0, qb, nullptr, EDIM);
    vtrans_kernel<<<dim3(LSEQ/64, BATCH*NH), 256, 0, stream>>>(qkv, vT);

    // fused causal attention: S/P never touch HBM
    flash_kernel<<<dim3(LSEQ/128, BATCH*NH), 256, 0, stream>>>(qkv, vT, o);

    gemm_bt<128,64,4,1,EPI_BIAS_RES_F32><<<dim3(EDIM/64, MTOK/128, 1), 256, 0, stream>>>(
        o, EDIM, 0, wT_proj, EDIM, 0, x, EDIM, 0, pb, x, EDIM);
    ln_kernel<<<MTOK, 256, 0, stream>>>(x, g2, be2, h);
    gemm_bt<128,128,2,2,EPI_BIAS_GELU_BF16><<<dim3(E4/128, MTOK/128, 1), 256, 0, stream>>>(
        h, EDIM, 0, wT_w1, EDIM, 0, mh, E4, 0, m1b, nullptr, EDIM);
    gemm_bt<128,64,4,1,EPI_BIAS_RES_F32><<<dim3(EDIM/64, MTOK/128, 1), 256, 0, stream>>>(
        mh, E4, 0, wT_w2, E4, 0, x, EDIM, 0, m2b, x, E4);
  }

  head_kernel<<<BATCH * KCTX, 256, 0, stream>>>(x, w_out, b_out, (float*)d_out);
}